// Round 1
// baseline (77.116 us; speedup 1.0000x reference)
//
#include <hip/hip_runtime.h>
#include <math.h>

#define NQ   4
#define NL   2
#define CD   128      // C
#define HWSZ 16384    // H*W
#define OUTC 128      // OUT

// ---------------------------------------------------------------------------
// Setup kernel: build M[4][16][16] (real symmetric quadratic forms) from the
// fixed circuit weights. z_w(pixel) = psi0^T M_w psi0 where psi0 is the real
// RY product state. Runs once per launch, 1 block, trivial cost.
// ---------------------------------------------------------------------------
__global__ void qsetup_kernel(const float* __restrict__ qw, float* __restrict__ M) {
    __shared__ float Ur[16][17];  // Ur[col][k] = Re U[k][col]
    __shared__ float Ui[16][17];
    const int tid = threadIdx.x;

    if (tid < 16) {
        // simulate circuit applied to basis vector e_tid
        float sr[16], si[16];
        #pragma unroll
        for (int k = 0; k < 16; ++k) { sr[k] = (k == tid) ? 1.f : 0.f; si[k] = 0.f; }

        #pragma unroll
        for (int l = 0; l < NL; ++l) {
            #pragma unroll
            for (int w = 0; w < NQ; ++w) {
                float phi = qw[(l * NQ + w) * 3 + 0];
                float th  = qw[(l * NQ + w) * 3 + 1];
                float om  = qw[(l * NQ + w) * 3 + 2];
                float ct = cosf(0.5f * th), st = sinf(0.5f * th);
                float a = 0.5f * (phi + om), b = 0.5f * (phi - om);
                float sa, ca, sb, cb;
                sincosf(a, &sa, &ca);
                sincosf(b, &sb, &cb);
                // Rot(phi,theta,omega): [[e^{-ia}ct, -e^{ib}st],[e^{-ib}st, e^{ia}ct]]
                float u00r =  ca * ct, u00i = -sa * ct;
                float u01r = -cb * st, u01i = -sb * st;
                float u10r =  cb * st, u10i = -sb * st;
                float u11r =  ca * ct, u11i =  sa * ct;
                const int wm = 1 << (3 - w);
                #pragma unroll
                for (int i = 0; i < 16; ++i) {
                    if (i & wm) continue;
                    int i1 = i | wm;
                    float a0r = sr[i],  a0i = si[i];
                    float a1r = sr[i1], a1i = si[i1];
                    sr[i]  = u00r * a0r - u00i * a0i + u01r * a1r - u01i * a1i;
                    si[i]  = u00r * a0i + u00i * a0r + u01r * a1i + u01i * a1r;
                    sr[i1] = u10r * a0r - u10i * a0i + u11r * a1r - u11i * a1i;
                    si[i1] = u10r * a0i + u10i * a0r + u11r * a1i + u11i * a1r;
                }
            }
            const int r = l % (NQ - 1) + 1;
            #pragma unroll
            for (int w = 0; w < NQ; ++w) {
                const int cm = 1 << (3 - w);
                const int tm = 1 << (3 - ((w + r) % NQ));
                #pragma unroll
                for (int i = 0; i < 16; ++i) {
                    if ((i & cm) && !(i & tm)) {
                        int i1 = i | tm;
                        float t;
                        t = sr[i]; sr[i] = sr[i1]; sr[i1] = t;
                        t = si[i]; si[i] = si[i1]; si[i1] = t;
                    }
                }
            }
        }
        #pragma unroll
        for (int k = 0; k < 16; ++k) { Ur[tid][k] = sr[k]; Ui[tid][k] = si[k]; }
    }
    __syncthreads();

    // M[w][i][j] = sum_k sgn_w(k) * (Ur[i][k]*Ur[j][k] + Ui[i][k]*Ui[j][k])
    for (int t = threadIdx.x; t < 4 * 16 * 16; t += blockDim.x) {
        int w = t >> 8, rem = t & 255, i = rem >> 4, j = rem & 15;
        float acc = 0.f;
        #pragma unroll
        for (int k = 0; k < 16; ++k) {
            float sgn = ((k >> (3 - w)) & 1) ? -1.f : 1.f;
            acc += sgn * (Ur[i][k] * Ur[j][k] + Ui[i][k] * Ui[j][k]);
        }
        M[t] = acc;
    }
}

// ---------------------------------------------------------------------------
// Main fused kernel: one thread per pixel.
//   xq = x[n,:,h,w] . pre_w^T + pre_b           (coalesced strided reads)
//   psi0 = RY product state (real, 16)
//   z_w  = psi0^T M_w psi0
//   out[n,:,h,w] = z . post_w^T + post_b        (coalesced strided writes)
// ---------------------------------------------------------------------------
__global__ __launch_bounds__(256) void qmain_kernel(
    const float* __restrict__ x, const float* __restrict__ pre_w,
    const float* __restrict__ pre_b, const float* __restrict__ M,
    const float* __restrict__ post_w, const float* __restrict__ post_b,
    float* __restrict__ out)
{
    __shared__ float s_pw[NQ * CD];       // pre_w, (4,128) row-major
    __shared__ float s_pb[NQ];
    __shared__ float s_M[NQ * 16 * 16];   // 4KB
    __shared__ float s_ow[OUTC * NQ];     // post_w, (128,4) row-major
    __shared__ float s_ob[OUTC];

    const int tid = threadIdx.x;
    for (int t = tid; t < NQ * CD; t += 256)   s_pw[t] = pre_w[t];
    if (tid < NQ)                              s_pb[tid] = pre_b[tid];
    for (int t = tid; t < NQ * 256; t += 256)  s_M[t] = M[t];
    for (int t = tid; t < OUTC * NQ; t += 256) s_ow[t] = post_w[t];
    for (int t = tid; t < OUTC; t += 256)      s_ob[t] = post_b[t];
    __syncthreads();

    const int p  = blockIdx.x * 256 + tid;   // pixel id, B = N*H*W
    const int n  = p >> 14;                  // / HWSZ
    const int hw = p & (HWSZ - 1);
    const float* xp = x + (size_t)n * CD * HWSZ + hw;

    float acc0 = s_pb[0], acc1 = s_pb[1], acc2 = s_pb[2], acc3 = s_pb[3];
    #pragma unroll 8
    for (int c = 0; c < CD; ++c) {
        float xv = xp[(size_t)c * HWSZ];
        acc0 += xv * s_pw[0 * CD + c];
        acc1 += xv * s_pw[1 * CD + c];
        acc2 += xv * s_pw[2 * CD + c];
        acc3 += xv * s_pw[3 * CD + c];
    }

    const float HPI = 1.5707963267948966f;
    float c0, s0, c1, s1, c2, s2, c3, s3;
    sincosf(HPI * acc0, &s0, &c0);
    sincosf(HPI * acc1, &s1, &c1);
    sincosf(HPI * acc2, &s2, &c2);
    sincosf(HPI * acc3, &s3, &c3);

    // psi0[b0*8+b1*4+b2*2+b3] = t0[b0]*t1[b1]*t2[b2]*t3[b3], t[0]=c, t[1]=s
    float v01[4] = { c0 * c1, c0 * s1, s0 * c1, s0 * s1 };
    float v23[4] = { c2 * c3, c2 * s3, s2 * c3, s2 * s3 };
    float e[16];
    #pragma unroll
    for (int a = 0; a < 4; ++a)
        #pragma unroll
        for (int b = 0; b < 4; ++b)
            e[a * 4 + b] = v01[a] * v23[b];

    float z[4];
    #pragma unroll
    for (int w = 0; w < 4; ++w) {
        float zz = 0.f;
        #pragma unroll
        for (int i = 0; i < 16; ++i) {
            float u = 0.f;
            #pragma unroll
            for (int j = 0; j < 16; ++j) u += s_M[(w * 16 + i) * 16 + j] * e[j];
            zz += u * e[i];
        }
        z[w] = zz;
    }

    float* op = out + (size_t)n * OUTC * HWSZ + hw;
    #pragma unroll 8
    for (int o = 0; o < OUTC; ++o) {
        float val = s_ob[o] + z[0] * s_ow[o * NQ + 0] + z[1] * s_ow[o * NQ + 1]
                            + z[2] * s_ow[o * NQ + 2] + z[3] * s_ow[o * NQ + 3];
        op[(size_t)o * HWSZ] = val;
    }
}

extern "C" void kernel_launch(void* const* d_in, const int* in_sizes, int n_in,
                              void* d_out, int out_size, void* d_ws, size_t ws_size,
                              hipStream_t stream) {
    const float* x      = (const float*)d_in[0];
    const float* pre_w  = (const float*)d_in[1];
    const float* pre_b  = (const float*)d_in[2];
    const float* qw     = (const float*)d_in[3];
    const float* post_w = (const float*)d_in[4];
    const float* post_b = (const float*)d_in[5];
    float* out = (float*)d_out;
    float* M   = (float*)d_ws;   // 4*16*16 floats = 4KB scratch

    hipLaunchKernelGGL(qsetup_kernel, dim3(1), dim3(256), 0, stream, qw, M);

    const int B = in_sizes[0] / CD;   // N*H*W pixels
    hipLaunchKernelGGL(qmain_kernel, dim3(B / 256), dim3(256), 0, stream,
                       x, pre_w, pre_b, M, post_w, post_b, out);
}

// Round 2
// 42.027 us; speedup vs baseline: 1.8349x; 1.8349x over previous
//
#include <hip/hip_runtime.h>
#include <math.h>

#define NQ   4
#define NL   2
#define CD   128      // C
#define HWSZ 16384    // H*W
#define OUTC 128      // OUT

// ---------------------------------------------------------------------------
// Setup kernel: build A[4][81] Pauli-string coefficients from circuit weights.
//   z_w(pixel) = sum_j A[w][j] * prod_i t_{i, j_i},  t_i = (1, cos(pi*xq_i), sin(pi*xq_i))
// Derivation: psi0 real product state -> rho = (x)_i 0.5*(I + cZ + sX);
//   z_w = tr(M_w rho), M_w the (real symmetric) quadratic form of the fixed circuit.
// 1 block, trivial cost, runs inside the graph each replay.
// ---------------------------------------------------------------------------
__global__ void qsetup_kernel(const float* __restrict__ qw, float* __restrict__ A) {
    __shared__ float Ur[16][17];  // Ur[col][k] = Re U[k][col]
    __shared__ float Ui[16][17];
    __shared__ float sM[4][16][16];
    const int tid = threadIdx.x;

    if (tid < 16) {
        // simulate circuit applied to basis vector e_tid
        float sr[16], si[16];
        #pragma unroll
        for (int k = 0; k < 16; ++k) { sr[k] = (k == tid) ? 1.f : 0.f; si[k] = 0.f; }

        #pragma unroll
        for (int l = 0; l < NL; ++l) {
            #pragma unroll
            for (int w = 0; w < NQ; ++w) {
                float phi = qw[(l * NQ + w) * 3 + 0];
                float th  = qw[(l * NQ + w) * 3 + 1];
                float om  = qw[(l * NQ + w) * 3 + 2];
                float ct = cosf(0.5f * th), st = sinf(0.5f * th);
                float a = 0.5f * (phi + om), b = 0.5f * (phi - om);
                float sa, ca, sb, cb;
                sincosf(a, &sa, &ca);
                sincosf(b, &sb, &cb);
                // Rot(phi,theta,omega): [[e^{-ia}ct, -e^{ib}st],[e^{-ib}st, e^{ia}ct]]
                float u00r =  ca * ct, u00i = -sa * ct;
                float u01r = -cb * st, u01i = -sb * st;
                float u10r =  cb * st, u10i = -sb * st;
                float u11r =  ca * ct, u11i =  sa * ct;
                const int wm = 1 << (3 - w);
                #pragma unroll
                for (int i = 0; i < 16; ++i) {
                    if (i & wm) continue;
                    int i1 = i | wm;
                    float a0r = sr[i],  a0i = si[i];
                    float a1r = sr[i1], a1i = si[i1];
                    sr[i]  = u00r * a0r - u00i * a0i + u01r * a1r - u01i * a1i;
                    si[i]  = u00r * a0i + u00i * a0r + u01r * a1i + u01i * a1r;
                    sr[i1] = u10r * a0r - u10i * a0i + u11r * a1r - u11i * a1i;
                    si[i1] = u10r * a0i + u10i * a0r + u11r * a1i + u11i * a1r;
                }
            }
            const int r = l % (NQ - 1) + 1;
            #pragma unroll
            for (int w = 0; w < NQ; ++w) {
                const int cm = 1 << (3 - w);
                const int tm = 1 << (3 - ((w + r) % NQ));
                #pragma unroll
                for (int i = 0; i < 16; ++i) {
                    if ((i & cm) && !(i & tm)) {
                        int i1 = i | tm;
                        float t;
                        t = sr[i]; sr[i] = sr[i1]; sr[i1] = t;
                        t = si[i]; si[i] = si[i1]; si[i1] = t;
                    }
                }
            }
        }
        #pragma unroll
        for (int k = 0; k < 16; ++k) { Ur[tid][k] = sr[k]; Ui[tid][k] = si[k]; }
    }
    __syncthreads();

    // sM[w][i][j] = sum_k sgn_w(k) * (Ur[i][k]*Ur[j][k] + Ui[i][k]*Ui[j][k])
    for (int t = tid; t < 4 * 16 * 16; t += blockDim.x) {
        int w = t >> 8, rem = t & 255, i = rem >> 4, j = rem & 15;
        float acc = 0.f;
        #pragma unroll
        for (int k = 0; k < 16; ++k) {
            float sgn = ((k >> (3 - w)) & 1) ? -1.f : 1.f;
            acc += sgn * (Ur[i][k] * Ur[j][k] + Ui[i][k] * Ui[j][k]);
        }
        sM[w][i >> 4 ? 0 : 0][0] = 0.f;  // dummy to keep layout simple (overwritten below)
        ((float*)sM)[t] = acc;
    }
    __syncthreads();

    // A[w][j] = (1/16) * tr(M_w P_j);  P_j = tensor of {I,Z,X} per wire, wire w0 <-> bit 3
    for (int t = tid; t < 4 * 81; t += blockDim.x) {
        int w = t / 81, j = t % 81;
        int j0 = j / 27, j1 = (j / 9) % 3, j2 = (j / 3) % 3, j3 = j % 3;
        int f =  ((j0 == 2) ? 8 : 0) | ((j1 == 2) ? 4 : 0)
               | ((j2 == 2) ? 2 : 0) | ((j3 == 2) ? 1 : 0);   // X flip mask
        int zm = ((j0 == 1) ? 8 : 0) | ((j1 == 1) ? 4 : 0)
               | ((j2 == 1) ? 2 : 0) | ((j3 == 1) ? 1 : 0);   // Z sign mask
        float acc = 0.f;
        #pragma unroll
        for (int i = 0; i < 16; ++i) {
            float sgn = (__popc(i & zm) & 1) ? -1.f : 1.f;
            acc += sM[w][i ^ f][i] * sgn;
        }
        A[t] = acc * 0.0625f;
    }
}

// ---------------------------------------------------------------------------
// Main fused kernel: one thread per pixel, NO LDS. All weight reads are
// wave-uniform -> scalar loads via constant cache.
// ---------------------------------------------------------------------------
__global__ __launch_bounds__(256, 4) void qmain_kernel(
    const float* __restrict__ x, const float* __restrict__ pre_w,
    const float* __restrict__ pre_b, const float* __restrict__ A,
    const float* __restrict__ post_w, const float* __restrict__ post_b,
    float* __restrict__ out)
{
    const int tid = threadIdx.x;
    const int p  = blockIdx.x * 256 + tid;   // pixel id
    const int n  = p >> 14;                  // / HWSZ
    const int hw = p & (HWSZ - 1);
    const float* xp = x + (size_t)n * CD * HWSZ + hw;

    float a0 = pre_b[0], a1 = pre_b[1], a2 = pre_b[2], a3 = pre_b[3];
    #pragma unroll 16
    for (int c = 0; c < CD; ++c) {
        float xv = __builtin_nontemporal_load(&xp[(size_t)c * HWSZ]);
        a0 = fmaf(xv, pre_w[0 * CD + c], a0);
        a1 = fmaf(xv, pre_w[1 * CD + c], a1);
        a2 = fmaf(xv, pre_w[2 * CD + c], a2);
        a3 = fmaf(xv, pre_w[3 * CD + c], a3);
    }

    const float PI = 3.14159265358979323846f;
    float cz0, sx0, cz1, sx1, cz2, sx2, cz3, sx3;
    sincosf(PI * a0, &sx0, &cz0);
    sincosf(PI * a1, &sx1, &cz1);
    sincosf(PI * a2, &sx2, &cz2);
    sincosf(PI * a3, &sx3, &cz3);

    // pair products of t_i = (1, cos, sin)
    float g01[9], g23[9];
    {
        float t0[3] = { 1.f, cz0, sx0 }, t1[3] = { 1.f, cz1, sx1 };
        float t2[3] = { 1.f, cz2, sx2 }, t3[3] = { 1.f, cz3, sx3 };
        #pragma unroll
        for (int a = 0; a < 3; ++a)
            #pragma unroll
            for (int b = 0; b < 3; ++b) {
                g01[a * 3 + b] = t0[a] * t1[b];
                g23[a * 3 + b] = t2[a] * t3[b];
            }
    }

    float z0 = 0.f, z1 = 0.f, z2 = 0.f, z3 = 0.f;
    #pragma unroll
    for (int j01 = 0; j01 < 9; ++j01)
        #pragma unroll
        for (int j23 = 0; j23 < 9; ++j23) {
            float g = g01[j01] * g23[j23];
            int j = j01 * 9 + j23;
            z0 = fmaf(A[  0 + j], g, z0);
            z1 = fmaf(A[ 81 + j], g, z1);
            z2 = fmaf(A[162 + j], g, z2);
            z3 = fmaf(A[243 + j], g, z3);
        }

    float* op = out + (size_t)n * OUTC * HWSZ + hw;
    #pragma unroll 8
    for (int o = 0; o < OUTC; ++o) {
        float val = fmaf(z0, post_w[o * NQ + 0],
                    fmaf(z1, post_w[o * NQ + 1],
                    fmaf(z2, post_w[o * NQ + 2],
                    fmaf(z3, post_w[o * NQ + 3], post_b[o]))));
        __builtin_nontemporal_store(val, &op[(size_t)o * HWSZ]);
    }
}

extern "C" void kernel_launch(void* const* d_in, const int* in_sizes, int n_in,
                              void* d_out, int out_size, void* d_ws, size_t ws_size,
                              hipStream_t stream) {
    const float* x      = (const float*)d_in[0];
    const float* pre_w  = (const float*)d_in[1];
    const float* pre_b  = (const float*)d_in[2];
    const float* qw     = (const float*)d_in[3];
    const float* post_w = (const float*)d_in[4];
    const float* post_b = (const float*)d_in[5];
    float* out = (float*)d_out;
    float* A   = (float*)d_ws;   // 4*81 floats

    hipLaunchKernelGGL(qsetup_kernel, dim3(1), dim3(256), 0, stream, qw, A);

    const int B = in_sizes[0] / CD;   // N*H*W pixels
    hipLaunchKernelGGL(qmain_kernel, dim3(B / 256), dim3(256), 0, stream,
                       x, pre_w, pre_b, A, post_w, post_b, out);
}

// Round 4
// 39.206 us; speedup vs baseline: 1.9669x; 1.0719x over previous
//
#include <hip/hip_runtime.h>
#include <math.h>

#define NQ   4
#define NL   2
#define CD   128      // C
#define HWSZ 16384    // H*W
#define OUTC 128      // OUT

// ---------------------------------------------------------------------------
// Setup kernel: build A[4][81] Pauli-string coefficients from circuit weights.
//   z_w(pixel) = sum_j A[w][j] * prod_i t_{i, j_i},  t_i = (1, cos(pi*xq_i), sin(pi*xq_i))
// Derivation: psi0 real product state -> rho = (x)_i 0.5*(I + cZ + sX);
//   z_w = tr(M_w rho), M_w the real symmetric quadratic form of the fixed circuit.
// ---------------------------------------------------------------------------
__global__ void qsetup_kernel(const float* __restrict__ qw, float* __restrict__ A) {
    __shared__ float Ur[16][17];  // Ur[col][k] = Re U[k][col]
    __shared__ float Ui[16][17];
    __shared__ float sM[4 * 16 * 16];
    const int tid = threadIdx.x;

    if (tid < 16) {
        float sr[16], si[16];
        #pragma unroll
        for (int k = 0; k < 16; ++k) { sr[k] = (k == tid) ? 1.f : 0.f; si[k] = 0.f; }

        #pragma unroll
        for (int l = 0; l < NL; ++l) {
            #pragma unroll
            for (int w = 0; w < NQ; ++w) {
                float phi = qw[(l * NQ + w) * 3 + 0];
                float th  = qw[(l * NQ + w) * 3 + 1];
                float om  = qw[(l * NQ + w) * 3 + 2];
                float ct = cosf(0.5f * th), st = sinf(0.5f * th);
                float a = 0.5f * (phi + om), b = 0.5f * (phi - om);
                float sa, ca, sb, cb;
                sincosf(a, &sa, &ca);
                sincosf(b, &sb, &cb);
                float u00r =  ca * ct, u00i = -sa * ct;
                float u01r = -cb * st, u01i = -sb * st;
                float u10r =  cb * st, u10i = -sb * st;
                float u11r =  ca * ct, u11i =  sa * ct;
                const int wm = 1 << (3 - w);
                #pragma unroll
                for (int i = 0; i < 16; ++i) {
                    if (i & wm) continue;
                    int i1 = i | wm;
                    float a0r = sr[i],  a0i = si[i];
                    float a1r = sr[i1], a1i = si[i1];
                    sr[i]  = u00r * a0r - u00i * a0i + u01r * a1r - u01i * a1i;
                    si[i]  = u00r * a0i + u00i * a0r + u01r * a1i + u01i * a1r;
                    sr[i1] = u10r * a0r - u10i * a0i + u11r * a1r - u11i * a1i;
                    si[i1] = u10r * a0i + u10i * a0r + u11r * a1i + u11i * a1r;
                }
            }
            const int r = l % (NQ - 1) + 1;
            #pragma unroll
            for (int w = 0; w < NQ; ++w) {
                const int cm = 1 << (3 - w);
                const int tm = 1 << (3 - ((w + r) % NQ));
                #pragma unroll
                for (int i = 0; i < 16; ++i) {
                    if ((i & cm) && !(i & tm)) {
                        int i1 = i | tm;
                        float t;
                        t = sr[i]; sr[i] = sr[i1]; sr[i1] = t;
                        t = si[i]; si[i] = si[i1]; si[i1] = t;
                    }
                }
            }
        }
        #pragma unroll
        for (int k = 0; k < 16; ++k) { Ur[tid][k] = sr[k]; Ui[tid][k] = si[k]; }
    }
    __syncthreads();

    // sM[w][i][j] = sum_k sgn_w(k) * (Ur[i][k]*Ur[j][k] + Ui[i][k]*Ui[j][k])
    for (int t = tid; t < 4 * 16 * 16; t += blockDim.x) {
        int w = t >> 8, rem = t & 255, i = rem >> 4, j = rem & 15;
        float acc = 0.f;
        #pragma unroll
        for (int k = 0; k < 16; ++k) {
            float sgn = ((k >> (3 - w)) & 1) ? -1.f : 1.f;
            acc += sgn * (Ur[i][k] * Ur[j][k] + Ui[i][k] * Ui[j][k]);
        }
        sM[t] = acc;
    }
    __syncthreads();

    // A[w][j] = (1/16) * tr(M_w P_j);  P_j = tensor of {I,Z,X} per wire
    for (int t = tid; t < 4 * 81; t += blockDim.x) {
        int w = t / 81, j = t % 81;
        int j0 = j / 27, j1 = (j / 9) % 3, j2 = (j / 3) % 3, j3 = j % 3;
        int f =  ((j0 == 2) ? 8 : 0) | ((j1 == 2) ? 4 : 0)
               | ((j2 == 2) ? 2 : 0) | ((j3 == 2) ? 1 : 0);   // X flip mask
        int zm = ((j0 == 1) ? 8 : 0) | ((j1 == 1) ? 4 : 0)
               | ((j2 == 1) ? 2 : 0) | ((j3 == 1) ? 1 : 0);   // Z sign mask
        float acc = 0.f;
        #pragma unroll
        for (int i = 0; i < 16; ++i) {
            float sgn = (__popc(i & zm) & 1) ? -1.f : 1.f;
            acc += sM[(w * 16 + (i ^ f)) * 16 + i] * sgn;
        }
        A[t] = acc * 0.0625f;
    }
}

// ---------------------------------------------------------------------------
// Main fused kernel: one thread per pixel, no LDS, no DMA. Memory-level
// parallelism forced by batching 32 channel loads into an explicit register
// array (all loads issued before first consume -> 32 outstanding vmem ops
// per lane; incremental vmcnt drain into the FMA chain). All weight reads
// are wave-uniform -> scalar loads. Coalesced nontemporal dword stores.
// ---------------------------------------------------------------------------
__global__ __launch_bounds__(256) void qmain_kernel(
    const float* __restrict__ x, const float* __restrict__ pre_w,
    const float* __restrict__ pre_b, const float* __restrict__ A,
    const float* __restrict__ post_w, const float* __restrict__ post_b,
    float* __restrict__ out)
{
    const int tid = threadIdx.x;
    const int p  = blockIdx.x * 256 + tid;   // pixel id
    const int n  = p >> 14;                  // / HWSZ
    const int hw = p & (HWSZ - 1);
    const float* xp = x + (size_t)n * CD * HWSZ + hw;

    float a0 = pre_b[0], a1 = pre_b[1], a2 = pre_b[2], a3 = pre_b[3];

    #pragma unroll
    for (int c0 = 0; c0 < CD; c0 += 32) {
        float xv[32];
        #pragma unroll
        for (int j = 0; j < 32; ++j)
            xv[j] = __builtin_nontemporal_load(&xp[(size_t)(c0 + j) * HWSZ]);
        #pragma unroll
        for (int j = 0; j < 32; ++j) {
            const int c = c0 + j;
            a0 = fmaf(xv[j], pre_w[0 * CD + c], a0);
            a1 = fmaf(xv[j], pre_w[1 * CD + c], a1);
            a2 = fmaf(xv[j], pre_w[2 * CD + c], a2);
            a3 = fmaf(xv[j], pre_w[3 * CD + c], a3);
        }
    }

    const float PI = 3.14159265358979323846f;
    float cz0, sx0, cz1, sx1, cz2, sx2, cz3, sx3;
    sincosf(PI * a0, &sx0, &cz0);
    sincosf(PI * a1, &sx1, &cz1);
    sincosf(PI * a2, &sx2, &cz2);
    sincosf(PI * a3, &sx3, &cz3);

    // pair products of t_i = (1, cos, sin)
    float g01[9], g23[9];
    {
        float t0[3] = { 1.f, cz0, sx0 }, t1[3] = { 1.f, cz1, sx1 };
        float t2[3] = { 1.f, cz2, sx2 }, t3[3] = { 1.f, cz3, sx3 };
        #pragma unroll
        for (int a = 0; a < 3; ++a)
            #pragma unroll
            for (int b = 0; b < 3; ++b) {
                g01[a * 3 + b] = t0[a] * t1[b];
                g23[a * 3 + b] = t2[a] * t3[b];
            }
    }

    float z0 = 0.f, z1 = 0.f, z2 = 0.f, z3 = 0.f;
    #pragma unroll
    for (int j01 = 0; j01 < 9; ++j01)
        #pragma unroll
        for (int j23 = 0; j23 < 9; ++j23) {
            float g = g01[j01] * g23[j23];
            int j = j01 * 9 + j23;
            z0 = fmaf(A[  0 + j], g, z0);
            z1 = fmaf(A[ 81 + j], g, z1);
            z2 = fmaf(A[162 + j], g, z2);
            z3 = fmaf(A[243 + j], g, z3);
        }

    float* op = out + (size_t)n * OUTC * HWSZ + hw;
    #pragma unroll 8
    for (int o = 0; o < OUTC; ++o) {
        float val = fmaf(z0, post_w[o * NQ + 0],
                    fmaf(z1, post_w[o * NQ + 1],
                    fmaf(z2, post_w[o * NQ + 2],
                    fmaf(z3, post_w[o * NQ + 3], post_b[o]))));
        __builtin_nontemporal_store(val, &op[(size_t)o * HWSZ]);
    }
}

extern "C" void kernel_launch(void* const* d_in, const int* in_sizes, int n_in,
                              void* d_out, int out_size, void* d_ws, size_t ws_size,
                              hipStream_t stream) {
    const float* x      = (const float*)d_in[0];
    const float* pre_w  = (const float*)d_in[1];
    const float* pre_b  = (const float*)d_in[2];
    const float* qw     = (const float*)d_in[3];
    const float* post_w = (const float*)d_in[4];
    const float* post_b = (const float*)d_in[5];
    float* out = (float*)d_out;
    float* A   = (float*)d_ws;   // 4*81 floats

    hipLaunchKernelGGL(qsetup_kernel, dim3(1), dim3(256), 0, stream, qw, A);

    const int B = in_sizes[0] / CD;   // N*H*W pixels
    hipLaunchKernelGGL(qmain_kernel, dim3(B / 256), dim3(256), 0, stream,
                       x, pre_w, pre_b, A, post_w, post_b, out);
}